// Round 17
// baseline (72.756 us; speedup 1.0000x reference)
//
#include <hip/hip_runtime.h>
#include <cstdint>

#define DD   128
#define LL   128
#define MAT  (DD*DD)          // 16384 elements per matrix
#define ROWB 256              // bytes per bf16 row (128*2)

typedef float  f32x16 __attribute__((ext_vector_type(16)));
typedef short  bf16x8 __attribute__((ext_vector_type(8)));
typedef unsigned short u16_t;

// Static device storage (rebuilt every launch; deterministic).
__device__ u16_t g_M2 [64*4*MAT];    // level-1 products, plain
__device__ u16_t g_M2t[64*4*MAT];    // level-1 transposed, plain
__device__ u16_t g_M4t[32*16*MAT];   // level-2 M^T, FRAGMENT-TILED
__device__ u16_t g_F0 [256*MAT];     // chain-0 result: S0[c][k] = G1[c][k]
__device__ u16_t g_F1 [256*MAT];     // chain-1 result: W[k][c]  = G2[c][k]

__device__ __forceinline__ u16_t f2bf(float f){
  unsigned int x = __builtin_bit_cast(unsigned int, f);
  unsigned int r = (x + 0x7FFFu + ((x >> 16) & 1u)) >> 16;   // RNE
  return (u16_t)r;
}
__device__ __forceinline__ float bf2f(u16_t u){
  unsigned int x = ((unsigned int)u) << 16;
  return __builtin_bit_cast(float, x);
}
__device__ __forceinline__ f32x16 mfma32(bf16x8 a, bf16x8 b, f32x16 c){
  return __builtin_amdgcn_mfma_f32_32x32x16_bf16(a, b, c, 0, 0, 0);
}
__device__ __forceinline__ f32x16 zero16(){
  f32x16 z;
#pragma unroll
  for (int i = 0; i < 16; ++i) z[i] = 0.f;
  return z;
}
__device__ __forceinline__ unsigned cvtpk(float lo, float hi){
  unsigned r;
  asm("v_cvt_pk_bf16_f32 %0, %1, %2" : "=v"(r) : "v"(lo), "v"(hi));
  return r;
}
__device__ __forceinline__ void pl32swap(unsigned &a, unsigned &b){
  asm volatile("v_permlane32_swap_b32 %0, %1" : "+v"(a), "+v"(b));
}

// Load 8 fp32 and convert to bf16x8 with RNE (bit-identical to old k_convert).
__device__ __forceinline__ bf16x8 ld8f(const float* p){
  float4 v0 = *(const float4*)p;
  float4 v1 = *(const float4*)(p + 4);
  bf16x8 r;
  r[0] = (short)f2bf(v0.x); r[1] = (short)f2bf(v0.y);
  r[2] = (short)f2bf(v0.z); r[3] = (short)f2bf(v0.w);
  r[4] = (short)f2bf(v1.x); r[5] = (short)f2bf(v1.y);
  r[6] = (short)f2bf(v1.z); r[7] = (short)f2bf(v1.w);
  return r;
}

// 32KB global -> LDS linear copy via global_load_lds (width 16), 256 threads.
__device__ __forceinline__ void stage32k(char* dstLds, const u16_t* srcG, int ltid){
  int w4 = ltid >> 6, l = ltid & 63;
  const char* g = (const char*)srcG + w4*8192 + l*16;
  char* s = dstLds + w4*8192;                 // wave-uniform base
#pragma unroll
  for (int i = 0; i < 8; ++i){
    __builtin_amdgcn_global_load_lds(
      (const __attribute__((address_space(1))) unsigned int*)(uintptr_t)(g + i*1024),
      (__attribute__((address_space(3))) unsigned int*)(unsigned int)(uintptr_t)(s + i*1024),
      16, 0, 0);
  }
}

// ---------------- level 1 FUSED with fp32->bf16 convert ---------------------
// C = A[2p][q0] @ A[2p+1][q1], reading T (fp32) directly:
//   X rows: coalesced fp32 loads + inline f2bf (bit-identical to old g_A).
//   B: staged transposed into LDS bf16 with the CT swizzle convention
//      (scatter b16 writes / swizzled b128 reads — validated R2/R8 idiom),
//      bit-identical to old g_At.
// Outputs Z = C (plain), Zt = C^T (plain row-major [c][k]) — same as R8.
#define LDS_P1 (3*32768)

__global__ __launch_bounds__(256, 1) void k_prod1f(const float* __restrict__ T){
  extern __shared__ char ldsp[];
  u16_t* CT = (u16_t*)ldsp;             // C^T, swizzled rows
  u16_t* CR = (u16_t*)(ldsp + 32768);   // C,   swizzled rows
  char*  BT = ldsp + 65536;             // B^T (= A^T of right matrix), swizzled

  const int bid = blockIdx.x, tid = threadIdx.x;
  const int w = tid >> 6, lane = tid & 63, g = lane >> 5, ln = lane & 31;
  const int wr = (w >> 1) * 64, wc = (w & 1) * 64;

  int p = bid >> 2, c2 = bid & 3;
  const float* Xf = T + (size_t)((2*p)*2   + (c2 & 1))        * MAT;
  const float* Bf = T + (size_t)((2*p+1)*2 + ((c2 >> 1) & 1)) * MAT;
  u16_t* Z  = g_M2  + (size_t)bid*MAT;
  u16_t* Zt = g_M2t + (size_t)bid*MAT;

  // stage B^T: element (k,c) of B -> BT row c, col k (swizzled), bf16 RNE
#pragma unroll 4
  for (int i = 0; i < 64; ++i){
    int idx = tid + 256*i;
    int k = idx >> 7, c = idx & 127;
    *(u16_t*)(BT + c*ROWB + ((2*k) ^ ((c & 15) << 4))) = f2bf(Bf[idx]);
  }
  __syncthreads();

  f32x16 acc[2][2];
  acc[0][0] = zero16(); acc[0][1] = zero16();
  acc[1][0] = zero16(); acc[1][1] = zero16();

#pragma unroll
  for (int kw = 0; kw < 8; ++kw){
    int ko = kw*32 + g*16;         // byte offset; element offset = kw*16 + g*8
    int eo = kw*16 + g*8;
    bf16x8 a0 = ld8f(Xf + (wr + ln     )*128 + eo);
    bf16x8 a1 = ld8f(Xf + (wr + 32 + ln)*128 + eo);
    int cb0 = wc + ln, cb1 = wc + 32 + ln;
    bf16x8 b0 = *(const bf16x8*)(BT + cb0*ROWB + (ko ^ ((cb0 & 15) << 4)));
    bf16x8 b1 = *(const bf16x8*)(BT + cb1*ROWB + (ko ^ ((cb1 & 15) << 4)));
    acc[0][0] = mfma32(a0, b0, acc[0][0]);
    acc[0][1] = mfma32(a0, b1, acc[0][1]);
    acc[1][0] = mfma32(a1, b0, acc[1][0]);
    acc[1][1] = mfma32(a1, b1, acc[1][1]);
  }

#pragma unroll
  for (int mt = 0; mt < 2; ++mt){
#pragma unroll
    for (int nt = 0; nt < 2; ++nt){
      int c  = wc + nt*32 + ln;
      int xc = (c & 15) << 4;
      // C^T: packed b64 writes (4 consecutive C-rows per quad)
#pragma unroll
      for (int q = 0; q < 4; ++q){
        int r4 = wr + mt*32 + 8*q + 4*g;
        unsigned int lo = (unsigned)f2bf(acc[mt][nt][4*q+0]) | ((unsigned)f2bf(acc[mt][nt][4*q+1]) << 16);
        unsigned int hi = (unsigned)f2bf(acc[mt][nt][4*q+2]) | ((unsigned)f2bf(acc[mt][nt][4*q+3]) << 16);
        uint2 v; v.x = lo; v.y = hi;
        *(uint2*)((char*)CT + c*ROWB + ((2*r4) ^ xc)) = v;
      }
      // C: scattered b16 writes
#pragma unroll
      for (int i = 0; i < 16; ++i){
        int r = wr + mt*32 + (i & 3) + 8*(i >> 2) + 4*g;
        *(u16_t*)((char*)CR + r*ROWB + ((2*c) ^ ((r & 15) << 4))) = f2bf(acc[mt][nt][i]);
      }
    }
  }
  __syncthreads();

#pragma unroll
  for (int i = 0; i < 8; ++i){
    int o = (tid + 256*i) * 16;
    int row = o >> 8, wb = o & 255;
    int xr = (row & 15) << 4;
    uint4 vt = *(const uint4*)((const char*)CT + row*ROWB + (wb ^ xr));
    *(uint4*)((char*)Zt + o) = vt;
    uint4 vz = *(const uint4*)((const char*)CR + row*ROWB + (wb ^ xr));
    *(uint4*)((char*)Z + o) = vz;
  }
}

// ---------------- level 2: C = X @ Y (R8 level-2 path verbatim) -------------
// Zt = C^T in FRAGMENT-TILED layout (dense, 32KB):
//   chunk(rt,kw) at byte (rt*8+kw)*1024; within: lane(g*32+ln)*16 + j*2
//   holding element (row=32rt+ln, k=16kw+8g+j) of C^T.
__global__ __launch_bounds__(256, 1) void k_prod2(){
  __shared__ u16_t CT[MAT];   // C^T, swizzled rows
  const int bid = blockIdx.x, tid = threadIdx.x;
  const int w = tid >> 6, lane = tid & 63, g = lane >> 5, ln = lane & 31;
  const int wr = (w >> 1) * 64, wc = (w & 1) * 64;

  int gg = bid >> 4, c = bid & 15;
  const u16_t* X  = g_M2  + (size_t)((2*gg)*4   + (c & 3))  * MAT;
  const u16_t* Yt = g_M2t + (size_t)((2*gg+1)*4 + (c >> 2)) * MAT;
  u16_t* Zt = g_M4t + (size_t)bid*MAT;

  f32x16 acc[2][2];
  acc[0][0] = zero16(); acc[0][1] = zero16();
  acc[1][0] = zero16(); acc[1][1] = zero16();

#pragma unroll
  for (int kw = 0; kw < 8; ++kw){
    int ko = kw*32 + g*16;
    bf16x8 a0 = *(const bf16x8*)((const char*)X  + (wr + ln     )*ROWB + ko);
    bf16x8 a1 = *(const bf16x8*)((const char*)X  + (wr + 32 + ln)*ROWB + ko);
    bf16x8 b0 = *(const bf16x8*)((const char*)Yt + (wc + ln     )*ROWB + ko);
    bf16x8 b1 = *(const bf16x8*)((const char*)Yt + (wc + 32 + ln)*ROWB + ko);
    acc[0][0] = mfma32(a0, b0, acc[0][0]);
    acc[0][1] = mfma32(a0, b1, acc[0][1]);
    acc[1][0] = mfma32(a1, b0, acc[1][0]);
    acc[1][1] = mfma32(a1, b1, acc[1][1]);
  }

#pragma unroll
  for (int mt = 0; mt < 2; ++mt){
#pragma unroll
    for (int nt = 0; nt < 2; ++nt){
      int c0  = wc + nt*32 + ln;
      int xc = (c0 & 15) << 4;
      // C^T: packed b64 writes (4 consecutive C-rows per quad)
#pragma unroll
      for (int q = 0; q < 4; ++q){
        int r4 = wr + mt*32 + 8*q + 4*g;
        unsigned int lo = (unsigned)f2bf(acc[mt][nt][4*q+0]) | ((unsigned)f2bf(acc[mt][nt][4*q+1]) << 16);
        unsigned int hi = (unsigned)f2bf(acc[mt][nt][4*q+2]) | ((unsigned)f2bf(acc[mt][nt][4*q+3]) << 16);
        uint2 v; v.x = lo; v.y = hi;
        *(uint2*)((char*)CT + c0*ROWB + ((2*r4) ^ xc)) = v;
      }
    }
  }
  __syncthreads();

  // emit fragment-tiled image: o (uint4 idx) = rt*512 + kw*64 + g*32 + ln
#pragma unroll
  for (int i = 0; i < 8; ++i){
    int o = tid + 256*i;
    int lnn = o & 31, ggg = (o >> 5) & 1, kww = (o >> 6) & 7, rtt = o >> 9;
    int r = 32*rtt + lnn;
    int srcB = r*ROWB + ((32*kww + 16*ggg) ^ ((r & 15) << 4));
    uint4 vt = *(const uint4*)((const char*)CT + srcB);
    *(uint4*)((char*)Zt + o*16) = vt;
  }
}

// ---------------- main: one half-chain per block (R8 verbatim) --------------
// Block (b, half): F_{s+1} = M_{16*half+s}^T F_s, s=0..15 -> F = G_{half+1}^T.
// Wave w owns cols 32w..32w+31 of F as MFMA B-fragments:
// F[kw] = bf16x8, lane (g,ln) holds F[k=16kw+8g+j][32w+ln], j=0..7.
// M^T A-fragments: fragment-tiled 32KB image, double-buffered in LDS.
#define LDS_MAIN (2*32768 + 64)

__global__ __launch_bounds__(256, 1) void k_main(const int* __restrict__ x){
  extern __shared__ char lds[];
  char* bufs  = lds;                         // 2 x 32KB
  int*  combo = (int*)(lds + 2*32768);       // 16 ints

  const int bid = blockIdx.x;
  const int b = bid & 255, half = bid >> 8;
  const int tid = threadIdx.x;
  const int w = tid >> 6, lane = tid & 63, g = lane >> 5, ln = lane & 31;

  if (tid < 16){
    const int* xb = x + b*LL + (half*16 + tid)*4;
    combo[tid] = (xb[0] & 1) | ((xb[1] & 1) << 1) | ((xb[2] & 1) << 2) | ((xb[3] & 1) << 3);
  }

  // F = I
  uint4 F[8];
#pragma unroll
  for (int kw = 0; kw < 8; ++kw){
    unsigned wd[4] = {0u,0u,0u,0u};
#pragma unroll
    for (int j = 0; j < 8; ++j){
      int k = 16*kw + 8*g + j;
      if (k == 32*w + ln) wd[j >> 1] |= 0x3F80u << (16*(j & 1));
    }
    uint4 v; v.x = wd[0]; v.y = wd[1]; v.z = wd[2]; v.w = wd[3];
    F[kw] = v;
  }
  __syncthreads();   // combo visible

  // prologue: stage group half*16 into buf0
  stage32k(bufs, g_M4t + (size_t)((half*16)*16 + combo[0])*MAT, tid);
  __syncthreads();   // drains vmcnt

  for (int s = 0; s < 16; ++s){
    const char* Mc = bufs + (s & 1)*32768;
    char*       Mn = bufs + ((s + 1) & 1)*32768;
    if (s + 1 < 16){
      stage32k(Mn, g_M4t + (size_t)((half*16 + s + 1)*16 + combo[s+1])*MAT, tid);
    }

    const char* Ml = Mc + lane*16;

    f32x16 acc[4];
#pragma unroll
    for (int rt = 0; rt < 4; ++rt) acc[rt] = zero16();

#pragma unroll
    for (int kw = 0; kw < 8; ++kw){
      bf16x8 bb = __builtin_bit_cast(bf16x8, F[kw]);
#pragma unroll
      for (int rt = 0; rt < 4; ++rt){
        bf16x8 a = *(const bf16x8*)(Ml + (rt*8 + kw)*1024);
        acc[rt] = mfma32(a, bb, acc[rt]);
      }
    }

    // Rebuild F from acc via cvt_pk + permlane32_swap (T12).
#pragma unroll
    for (int rt = 0; rt < 4; ++rt){
      unsigned y0 = cvtpk(acc[rt][0],  acc[rt][1]);
      unsigned x0 = cvtpk(acc[rt][4],  acc[rt][5]);
      pl32swap(y0, x0);
      unsigned y1 = cvtpk(acc[rt][2],  acc[rt][3]);
      unsigned x1 = cvtpk(acc[rt][6],  acc[rt][7]);
      pl32swap(y1, x1);
      uint4 v0; v0.x = y0; v0.y = y1; v0.z = x0; v0.w = x1;
      F[2*rt] = v0;

      unsigned y2 = cvtpk(acc[rt][8],  acc[rt][9]);
      unsigned x2 = cvtpk(acc[rt][12], acc[rt][13]);
      pl32swap(y2, x2);
      unsigned y3 = cvtpk(acc[rt][10], acc[rt][11]);
      unsigned x3 = cvtpk(acc[rt][14], acc[rt][15]);
      pl32swap(y3, x3);
      uint4 v1; v1.x = y2; v1.y = y3; v1.z = x2; v1.w = x3;
      F[2*rt+1] = v1;
    }
    __syncthreads();  // all done with Mc; Mn staged (vmcnt drained)
  }

  // R8-validated epilogue (global stores, consumed by k_tail)
  const int c = 32*w + ln;
  if (half == 0){
    // S0[c][k] = G1[c][k]: row-major, vectorized 16B stores
    u16_t* dst = g_F0 + (size_t)b*MAT + c*128;
#pragma unroll
    for (int kw = 0; kw < 8; ++kw)
      *(uint4*)(dst + kw*16 + g*8) = F[kw];
  } else {
    // W[k][c] = G2[c][k]: row-major [k][c] -> scattered b16 stores
    u16_t* dst = g_F1 + (size_t)b*MAT + c;
#pragma unroll
    for (int kw = 0; kw < 8; ++kw){
      uint4 v = F[kw];
      unsigned wd[4] = {v.x, v.y, v.z, v.w};
#pragma unroll
      for (int j = 0; j < 8; ++j){
        int k = 16*kw + 8*g + j;
        u16_t bits = (u16_t)((j & 1) ? (wd[j >> 1] >> 16) : (wd[j >> 1] & 0xFFFF));
        dst[(size_t)k*128] = bits;
      }
    }
  }
}

// ---------------- tail: trace(G1@G2) = sum_flat S0*W, then log --------------
__global__ __launch_bounds__(256, 1) void k_tail(float* __restrict__ out,
                                                 int out_complex){
  __shared__ float red[4];
  const int b = blockIdx.x, tid = threadIdx.x;
  const int w = tid >> 6, lane = tid & 63;

  const u16_t* S0 = g_F0 + (size_t)b*MAT;
  const u16_t* W  = g_F1 + (size_t)b*MAT;

  float sum = 0.f;
#pragma unroll
  for (int i = 0; i < 8; ++i){
    int o = (i*256 + tid)*8;
    uint4 a = *(const uint4*)(S0 + o);
    uint4 v = *(const uint4*)(W  + o);
    unsigned aw[4] = {a.x, a.y, a.z, a.w};
    unsigned vw[4] = {v.x, v.y, v.z, v.w};
#pragma unroll
    for (int q = 0; q < 4; ++q){
      sum += bf2f((u16_t)(aw[q] & 0xFFFF)) * bf2f((u16_t)(vw[q] & 0xFFFF));
      sum += bf2f((u16_t)(aw[q] >> 16))    * bf2f((u16_t)(vw[q] >> 16));
    }
  }
#pragma unroll
  for (int off = 1; off < 64; off <<= 1) sum += __shfl_xor(sum, off, 64);
  if (lane == 0) red[w] = sum;
  __syncthreads();
  if (tid == 0){
    float s = red[0] + red[1] + red[2] + red[3];
    float re = logf(fabsf(s));
    float im = (s < 0.f) ? 3.14159265358979323f : 0.f;
    if (out_complex){ out[2*b] = re; out[2*b+1] = im; }
    else            { out[b] = re; }
  }
}

extern "C" void kernel_launch(void* const* d_in, const int* in_sizes, int n_in,
                              void* d_out, int out_size, void* d_ws, size_t ws_size,
                              hipStream_t stream){
  const int*   x = (const int*)d_in[0];
  const float* T = (const float*)d_in[1];
  int Bn = in_sizes[0] / LL;                   // 256
  int oc = (out_size >= 2*Bn) ? 1 : 0;

  (void)d_ws; (void)ws_size; (void)n_in;
  hipFuncSetAttribute(reinterpret_cast<const void*>(k_main),
                      hipFuncAttributeMaxDynamicSharedMemorySize, LDS_MAIN);
  hipFuncSetAttribute(reinterpret_cast<const void*>(k_prod1f),
                      hipFuncAttributeMaxDynamicSharedMemorySize, LDS_P1);

  k_prod1f<<<256,   256, LDS_P1, stream>>>(T);
  k_prod2 <<<512,   256, 0, stream>>>();
  k_main  <<<2*Bn,  256, LDS_MAIN, stream>>>(x);
  k_tail  <<<Bn,    256, 0, stream>>>((float*)d_out, oc);
}

// Round 18
// 71.284 us; speedup vs baseline: 1.0207x; 1.0207x over previous
//
#include <hip/hip_runtime.h>
#include <cstdint>

#define DD   128
#define LL   128
#define MAT  (DD*DD)          // 16384 elements per matrix
#define ROWB 256              // bytes per bf16 row (128*2)

typedef float  f32x16 __attribute__((ext_vector_type(16)));
typedef short  bf16x8 __attribute__((ext_vector_type(8)));
typedef unsigned short u16_t;

// Static device storage (rebuilt every launch; deterministic).
__device__ u16_t g_M2 [64*4*MAT];    // level-1 LEFT products (even p), plain
__device__ u16_t g_M2t[64*4*MAT];    // level-1 RIGHT products (odd p), transposed
__device__ u16_t g_M4t[32*16*MAT];   // level-2 M^T, FRAGMENT-TILED
__device__ u16_t g_F0 [256*MAT];     // chain-0 result: S0[c][k] = G1[c][k]
__device__ u16_t g_F1 [256*MAT];     // chain-1 result: W[k][c]  = G2[c][k]

__device__ __forceinline__ u16_t f2bf(float f){
  unsigned int x = __builtin_bit_cast(unsigned int, f);
  unsigned int r = (x + 0x7FFFu + ((x >> 16) & 1u)) >> 16;   // RNE
  return (u16_t)r;
}
__device__ __forceinline__ float bf2f(u16_t u){
  unsigned int x = ((unsigned int)u) << 16;
  return __builtin_bit_cast(float, x);
}
__device__ __forceinline__ f32x16 mfma32(bf16x8 a, bf16x8 b, f32x16 c){
  return __builtin_amdgcn_mfma_f32_32x32x16_bf16(a, b, c, 0, 0, 0);
}
__device__ __forceinline__ f32x16 zero16(){
  f32x16 z;
#pragma unroll
  for (int i = 0; i < 16; ++i) z[i] = 0.f;
  return z;
}
__device__ __forceinline__ unsigned cvtpk(float lo, float hi){
  unsigned r;
  asm("v_cvt_pk_bf16_f32 %0, %1, %2" : "=v"(r) : "v"(lo), "v"(hi));
  return r;
}
__device__ __forceinline__ void pl32swap(unsigned &a, unsigned &b){
  asm volatile("v_permlane32_swap_b32 %0, %1" : "+v"(a), "+v"(b));
}

// Load 8 fp32 and convert to bf16x8 with RNE (bit-identical to old k_convert).
__device__ __forceinline__ bf16x8 ld8f(const float* p){
  float4 v0 = *(const float4*)p;
  float4 v1 = *(const float4*)(p + 4);
  bf16x8 r;
  r[0] = (short)f2bf(v0.x); r[1] = (short)f2bf(v0.y);
  r[2] = (short)f2bf(v0.z); r[3] = (short)f2bf(v0.w);
  r[4] = (short)f2bf(v1.x); r[5] = (short)f2bf(v1.y);
  r[6] = (short)f2bf(v1.z); r[7] = (short)f2bf(v1.w);
  return r;
}

// 32KB global -> LDS linear copy via global_load_lds (width 16), 256 threads.
__device__ __forceinline__ void stage32k(char* dstLds, const u16_t* srcG, int ltid){
  int w4 = ltid >> 6, l = ltid & 63;
  const char* g = (const char*)srcG + w4*8192 + l*16;
  char* s = dstLds + w4*8192;                 // wave-uniform base
#pragma unroll
  for (int i = 0; i < 8; ++i){
    __builtin_amdgcn_global_load_lds(
      (const __attribute__((address_space(1))) unsigned int*)(uintptr_t)(g + i*1024),
      (__attribute__((address_space(3))) unsigned int*)(unsigned int)(uintptr_t)(s + i*1024),
      16, 0, 0);
  }
}

// ---------------- level 1 FUSED with fp32->bf16 convert ---------------------
// C = A[2p][q0] @ A[2p+1][q1], reading T (fp32) directly.
// Only the image prod2 actually consumes is built and written:
//   even p (LEFT  operand of level-2): plain  C  -> g_M2 [bid]
//   odd  p (RIGHT operand of level-2): transp C^T-> g_M2t[bid]
// LDS = BT (32KB) + one C-image (32KB) = 64KB -> 2 blocks/CU.
#define LDS_P1 (2*32768)

__global__ __launch_bounds__(256, 1) void k_prod1f(const float* __restrict__ T){
  extern __shared__ char ldsp[];
  u16_t* CI = (u16_t*)ldsp;             // C image (CR for left, CT for right)
  char*  BT = ldsp + 32768;             // B^T staged, swizzled rows

  const int bid = blockIdx.x, tid = threadIdx.x;
  const int w = tid >> 6, lane = tid & 63, g = lane >> 5, ln = lane & 31;
  const int wr = (w >> 1) * 64, wc = (w & 1) * 64;

  int p = bid >> 2, c2 = bid & 3;
  const float* Xf = T + (size_t)((2*p)*2   + (c2 & 1))        * MAT;
  const float* Bf = T + (size_t)((2*p+1)*2 + ((c2 >> 1) & 1)) * MAT;
  const bool left = ((p & 1) == 0);
  u16_t* Zo = (left ? g_M2 : g_M2t) + (size_t)bid*MAT;

  // stage B^T: element (k,c) of B -> BT row c, col k (swizzled), bf16 RNE
#pragma unroll 4
  for (int i = 0; i < 64; ++i){
    int idx = tid + 256*i;
    int k = idx >> 7, c = idx & 127;
    *(u16_t*)(BT + c*ROWB + ((2*k) ^ ((c & 15) << 4))) = f2bf(Bf[idx]);
  }
  __syncthreads();

  f32x16 acc[2][2];
  acc[0][0] = zero16(); acc[0][1] = zero16();
  acc[1][0] = zero16(); acc[1][1] = zero16();

#pragma unroll
  for (int kw = 0; kw < 8; ++kw){
    int ko = kw*32 + g*16;         // byte offset; element offset = kw*16 + g*8
    int eo = kw*16 + g*8;
    bf16x8 a0 = ld8f(Xf + (wr + ln     )*128 + eo);
    bf16x8 a1 = ld8f(Xf + (wr + 32 + ln)*128 + eo);
    int cb0 = wc + ln, cb1 = wc + 32 + ln;
    bf16x8 b0 = *(const bf16x8*)(BT + cb0*ROWB + (ko ^ ((cb0 & 15) << 4)));
    bf16x8 b1 = *(const bf16x8*)(BT + cb1*ROWB + (ko ^ ((cb1 & 15) << 4)));
    acc[0][0] = mfma32(a0, b0, acc[0][0]);
    acc[0][1] = mfma32(a0, b1, acc[0][1]);
    acc[1][0] = mfma32(a1, b0, acc[1][0]);
    acc[1][1] = mfma32(a1, b1, acc[1][1]);
  }

#pragma unroll
  for (int mt = 0; mt < 2; ++mt){
#pragma unroll
    for (int nt = 0; nt < 2; ++nt){
      int c  = wc + nt*32 + ln;
      int xc = (c & 15) << 4;
      if (!left){
        // C^T image: packed b64 writes (4 consecutive C-rows per quad)
#pragma unroll
        for (int q = 0; q < 4; ++q){
          int r4 = wr + mt*32 + 8*q + 4*g;
          unsigned int lo = (unsigned)f2bf(acc[mt][nt][4*q+0]) | ((unsigned)f2bf(acc[mt][nt][4*q+1]) << 16);
          unsigned int hi = (unsigned)f2bf(acc[mt][nt][4*q+2]) | ((unsigned)f2bf(acc[mt][nt][4*q+3]) << 16);
          uint2 v; v.x = lo; v.y = hi;
          *(uint2*)((char*)CI + c*ROWB + ((2*r4) ^ xc)) = v;
        }
      } else {
        // C plain image: scattered b16 writes
#pragma unroll
        for (int i = 0; i < 16; ++i){
          int r = wr + mt*32 + (i & 3) + 8*(i >> 2) + 4*g;
          *(u16_t*)((char*)CI + r*ROWB + ((2*c) ^ ((r & 15) << 4))) = f2bf(acc[mt][nt][i]);
        }
      }
    }
  }
  __syncthreads();

  // emit the single image, coalesced
#pragma unroll
  for (int i = 0; i < 8; ++i){
    int o = (tid + 256*i) * 16;
    int row = o >> 8, wb = o & 255;
    int xr = (row & 15) << 4;
    uint4 v = *(const uint4*)((const char*)CI + row*ROWB + (wb ^ xr));
    *(uint4*)((char*)Zo + o) = v;
  }
}

// ---------------- level 2: D = R^T @ L^T = (L@R)^T --------------------------
// X  = g_M2t[(2gg+1)*4 + (c>>2)]  (= R^T plain rows)
// Yt = g_M2 [(2gg)*4   + (c&3)]   (= L plain rows; Y = L^T)
// acc = D = C2^T — exactly the image g_M4t stores, so the plain-scatter (CR)
// write + validated emit produce the fragment-tiled image directly.
// Same products, same k-order as before -> bit-identical numerics.
__global__ __launch_bounds__(256, 1) void k_prod2(){
  __shared__ u16_t CI[MAT];   // D plain, swizzled rows
  const int bid = blockIdx.x, tid = threadIdx.x;
  const int w = tid >> 6, lane = tid & 63, g = lane >> 5, ln = lane & 31;
  const int wr = (w >> 1) * 64, wc = (w & 1) * 64;

  int gg = bid >> 4, c = bid & 15;
  const u16_t* X  = g_M2t + (size_t)((2*gg+1)*4 + (c >> 2)) * MAT;
  const u16_t* Yt = g_M2  + (size_t)((2*gg)*4   + (c & 3))  * MAT;
  u16_t* Zt = g_M4t + (size_t)bid*MAT;

  f32x16 acc[2][2];
  acc[0][0] = zero16(); acc[0][1] = zero16();
  acc[1][0] = zero16(); acc[1][1] = zero16();

#pragma unroll
  for (int kw = 0; kw < 8; ++kw){
    int ko = kw*32 + g*16;
    bf16x8 a0 = *(const bf16x8*)((const char*)X  + (wr + ln     )*ROWB + ko);
    bf16x8 a1 = *(const bf16x8*)((const char*)X  + (wr + 32 + ln)*ROWB + ko);
    bf16x8 b0 = *(const bf16x8*)((const char*)Yt + (wc + ln     )*ROWB + ko);
    bf16x8 b1 = *(const bf16x8*)((const char*)Yt + (wc + 32 + ln)*ROWB + ko);
    acc[0][0] = mfma32(a0, b0, acc[0][0]);
    acc[0][1] = mfma32(a0, b1, acc[0][1]);
    acc[1][0] = mfma32(a1, b0, acc[1][0]);
    acc[1][1] = mfma32(a1, b1, acc[1][1]);
  }

#pragma unroll
  for (int mt = 0; mt < 2; ++mt){
#pragma unroll
    for (int nt = 0; nt < 2; ++nt){
      int c0 = wc + nt*32 + ln;
      // D plain: scattered b16 writes (validated CR pattern)
#pragma unroll
      for (int i = 0; i < 16; ++i){
        int r = wr + mt*32 + (i & 3) + 8*(i >> 2) + 4*g;
        *(u16_t*)((char*)CI + r*ROWB + ((2*c0) ^ ((r & 15) << 4))) = f2bf(acc[mt][nt][i]);
      }
    }
  }
  __syncthreads();

  // emit fragment-tiled image: o (uint4 idx) = rt*512 + kw*64 + g*32 + ln
#pragma unroll
  for (int i = 0; i < 8; ++i){
    int o = tid + 256*i;
    int lnn = o & 31, ggg = (o >> 5) & 1, kww = (o >> 6) & 7, rtt = o >> 9;
    int r = 32*rtt + lnn;
    int srcB = r*ROWB + ((32*kww + 16*ggg) ^ ((r & 15) << 4));
    uint4 vt = *(const uint4*)((const char*)CI + srcB);
    *(uint4*)((char*)Zt + o*16) = vt;
  }
}

// ---------------- main: one half-chain per block (R8 verbatim) --------------
// Block (b, half): F_{s+1} = M_{16*half+s}^T F_s, s=0..15 -> F = G_{half+1}^T.
// Wave w owns cols 32w..32w+31 of F as MFMA B-fragments:
// F[kw] = bf16x8, lane (g,ln) holds F[k=16kw+8g+j][32w+ln], j=0..7.
// M^T A-fragments: fragment-tiled 32KB image, double-buffered in LDS.
#define LDS_MAIN (2*32768 + 64)

__global__ __launch_bounds__(256, 1) void k_main(const int* __restrict__ x){
  extern __shared__ char lds[];
  char* bufs  = lds;                         // 2 x 32KB
  int*  combo = (int*)(lds + 2*32768);       // 16 ints

  const int bid = blockIdx.x;
  const int b = bid & 255, half = bid >> 8;
  const int tid = threadIdx.x;
  const int w = tid >> 6, lane = tid & 63, g = lane >> 5, ln = lane & 31;

  if (tid < 16){
    const int* xb = x + b*LL + (half*16 + tid)*4;
    combo[tid] = (xb[0] & 1) | ((xb[1] & 1) << 1) | ((xb[2] & 1) << 2) | ((xb[3] & 1) << 3);
  }

  // F = I
  uint4 F[8];
#pragma unroll
  for (int kw = 0; kw < 8; ++kw){
    unsigned wd[4] = {0u,0u,0u,0u};
#pragma unroll
    for (int j = 0; j < 8; ++j){
      int k = 16*kw + 8*g + j;
      if (k == 32*w + ln) wd[j >> 1] |= 0x3F80u << (16*(j & 1));
    }
    uint4 v; v.x = wd[0]; v.y = wd[1]; v.z = wd[2]; v.w = wd[3];
    F[kw] = v;
  }
  __syncthreads();   // combo visible

  // prologue: stage group half*16 into buf0
  stage32k(bufs, g_M4t + (size_t)((half*16)*16 + combo[0])*MAT, tid);
  __syncthreads();   // drains vmcnt

  for (int s = 0; s < 16; ++s){
    const char* Mc = bufs + (s & 1)*32768;
    char*       Mn = bufs + ((s + 1) & 1)*32768;
    if (s + 1 < 16){
      stage32k(Mn, g_M4t + (size_t)((half*16 + s + 1)*16 + combo[s+1])*MAT, tid);
    }

    const char* Ml = Mc + lane*16;

    f32x16 acc[4];
#pragma unroll
    for (int rt = 0; rt < 4; ++rt) acc[rt] = zero16();

#pragma unroll
    for (int kw = 0; kw < 8; ++kw){
      bf16x8 bb = __builtin_bit_cast(bf16x8, F[kw]);
#pragma unroll
      for (int rt = 0; rt < 4; ++rt){
        bf16x8 a = *(const bf16x8*)(Ml + (rt*8 + kw)*1024);
        acc[rt] = mfma32(a, bb, acc[rt]);
      }
    }

    // Rebuild F from acc via cvt_pk + permlane32_swap (T12).
#pragma unroll
    for (int rt = 0; rt < 4; ++rt){
      unsigned y0 = cvtpk(acc[rt][0],  acc[rt][1]);
      unsigned x0 = cvtpk(acc[rt][4],  acc[rt][5]);
      pl32swap(y0, x0);
      unsigned y1 = cvtpk(acc[rt][2],  acc[rt][3]);
      unsigned x1 = cvtpk(acc[rt][6],  acc[rt][7]);
      pl32swap(y1, x1);
      uint4 v0; v0.x = y0; v0.y = y1; v0.z = x0; v0.w = x1;
      F[2*rt] = v0;

      unsigned y2 = cvtpk(acc[rt][8],  acc[rt][9]);
      unsigned x2 = cvtpk(acc[rt][12], acc[rt][13]);
      pl32swap(y2, x2);
      unsigned y3 = cvtpk(acc[rt][10], acc[rt][11]);
      unsigned x3 = cvtpk(acc[rt][14], acc[rt][15]);
      pl32swap(y3, x3);
      uint4 v1; v1.x = y2; v1.y = y3; v1.z = x2; v1.w = x3;
      F[2*rt+1] = v1;
    }
    __syncthreads();  // all done with Mc; Mn staged (vmcnt drained)
  }

  // R8-validated epilogue (global stores, consumed by k_tail)
  const int c = 32*w + ln;
  if (half == 0){
    // S0[c][k] = G1[c][k]: row-major, vectorized 16B stores
    u16_t* dst = g_F0 + (size_t)b*MAT + c*128;
#pragma unroll
    for (int kw = 0; kw < 8; ++kw)
      *(uint4*)(dst + kw*16 + g*8) = F[kw];
  } else {
    // W[k][c] = G2[c][k]: row-major [k][c] -> scattered b16 stores
    u16_t* dst = g_F1 + (size_t)b*MAT + c;
#pragma unroll
    for (int kw = 0; kw < 8; ++kw){
      uint4 v = F[kw];
      unsigned wd[4] = {v.x, v.y, v.z, v.w};
#pragma unroll
      for (int j = 0; j < 8; ++j){
        int k = 16*kw + 8*g + j;
        u16_t bits = (u16_t)((j & 1) ? (wd[j >> 1] >> 16) : (wd[j >> 1] & 0xFFFF));
        dst[(size_t)k*128] = bits;
      }
    }
  }
}

// ---------------- tail: trace(G1@G2) = sum_flat S0*W, then log --------------
__global__ __launch_bounds__(256, 1) void k_tail(float* __restrict__ out,
                                                 int out_complex){
  __shared__ float red[4];
  const int b = blockIdx.x, tid = threadIdx.x;
  const int w = tid >> 6, lane = tid & 63;

  const u16_t* S0 = g_F0 + (size_t)b*MAT;
  const u16_t* W  = g_F1 + (size_t)b*MAT;

  float sum = 0.f;
#pragma unroll
  for (int i = 0; i < 8; ++i){
    int o = (i*256 + tid)*8;
    uint4 a = *(const uint4*)(S0 + o);
    uint4 v = *(const uint4*)(W  + o);
    unsigned aw[4] = {a.x, a.y, a.z, a.w};
    unsigned vw[4] = {v.x, v.y, v.z, v.w};
#pragma unroll
    for (int q = 0; q < 4; ++q){
      sum += bf2f((u16_t)(aw[q] & 0xFFFF)) * bf2f((u16_t)(vw[q] & 0xFFFF));
      sum += bf2f((u16_t)(aw[q] >> 16))    * bf2f((u16_t)(vw[q] >> 16));
    }
  }
#pragma unroll
  for (int off = 1; off < 64; off <<= 1) sum += __shfl_xor(sum, off, 64);
  if (lane == 0) red[w] = sum;
  __syncthreads();
  if (tid == 0){
    float s = red[0] + red[1] + red[2] + red[3];
    float re = logf(fabsf(s));
    float im = (s < 0.f) ? 3.14159265358979323f : 0.f;
    if (out_complex){ out[2*b] = re; out[2*b+1] = im; }
    else            { out[b] = re; }
  }
}

extern "C" void kernel_launch(void* const* d_in, const int* in_sizes, int n_in,
                              void* d_out, int out_size, void* d_ws, size_t ws_size,
                              hipStream_t stream){
  const int*   x = (const int*)d_in[0];
  const float* T = (const float*)d_in[1];
  int Bn = in_sizes[0] / LL;                   // 256
  int oc = (out_size >= 2*Bn) ? 1 : 0;

  (void)d_ws; (void)ws_size; (void)n_in;
  hipFuncSetAttribute(reinterpret_cast<const void*>(k_main),
                      hipFuncAttributeMaxDynamicSharedMemorySize, LDS_MAIN);
  hipFuncSetAttribute(reinterpret_cast<const void*>(k_prod1f),
                      hipFuncAttributeMaxDynamicSharedMemorySize, LDS_P1);

  k_prod1f<<<256,   256, LDS_P1, stream>>>(T);
  k_prod2 <<<512,   256, 0, stream>>>();
  k_main  <<<2*Bn,  256, LDS_MAIN, stream>>>(x);
  k_tail  <<<Bn,    256, 0, stream>>>((float*)d_out, oc);
}